// Round 5
// baseline (187.626 us; speedup 1.0000x reference)
//
#include <hip/hip_runtime.h>
#include <math.h>

// Problem constants: B=8, D=8 (channels), H=256, W=256, M=256
#define HWPIX 65536
#define NMATCH 256
#define THETA_LEN 169
#define WSTRIDE 96   // dwords of packed weights per match in d_ws

// clang's amdgcn builtins use the __fp16 vector type ('h' in builtin sigs),
// NOT _Float16 — must match exactly for cvt_pkrtz / fdot2.
typedef __fp16 half_t;
typedef __fp16 half2_t __attribute__((ext_vector_type(2)));

__device__ __forceinline__ unsigned int pack_rne(float a, float b) {
    union { half2_t h; unsigned int u; } x;
    x.h.x = (half_t)a;   // v_cvt_f16_f32 (RNE)
    x.h.y = (half_t)b;
    return x.u;
}

__device__ __forceinline__ half2_t h2(unsigned int u) {
    union { unsigned int u; half2_t h; } x; x.u = u; return x.h;
}

// tanh-approx GELU (sigmoid form) on HW transcendentals — unchanged from R2/R3.
__device__ __forceinline__ float gelu_fast(float v) {
    float t = fmaf(v * v, 0.10294323f, 2.3022082f);
    float e = __builtin_amdgcn_exp2f(-v * t);
    float r = __builtin_amdgcn_rcpf(1.0f + e);
    return v * r;
}

// Pack theta (f32) into per-match half2 weight pairs + f32 biases.
// Layout (dword index within a match's 96-dword slot):
//   [0..39]  L0 pairs: o*5+p -> (w0[o][2p], w0[o][2p+1]); p=4 is the rel pair (k=8,9)
//   [40..47] L0 bias (f32)
//   [48..79] L1 pairs: o*4+p -> (w1[o][2p], w1[o][2p+1])
//   [80..87] L1 bias (f32)
//   [88..91] L2 pairs
//   [92]     b2 (f32)
__global__ __launch_bounds__(128) void prep_kernel(const float* __restrict__ theta,
                                                   unsigned int* __restrict__ wpk) {
    const int m = blockIdx.x;
    const int t = threadIdx.x;
    const float* __restrict__ th = theta + m * THETA_LEN;
    unsigned int v = 0;
    if (t < 40) {
        const int o = t / 5, p = t % 5;
        const int i0 = o * 10 + 2 * p;
        v = pack_rne(th[i0], th[i0 + 1]);
    } else if (t < 48) {
        v = __float_as_uint(th[80 + (t - 40)]);
    } else if (t < 80) {
        const int q = t - 48, o = q / 4, p = q % 4;
        const int i0 = 88 + o * 8 + 2 * p;
        v = pack_rne(th[i0], th[i0 + 1]);
    } else if (t < 88) {
        v = __float_as_uint(th[152 + (t - 80)]);
    } else if (t < 92) {
        const int q = t - 88;
        v = pack_rne(th[160 + 2 * q], th[161 + 2 * q]);
    } else if (t == 92) {
        v = __float_as_uint(th[168]);
    }
    if (t < 96) wpk[m * WSTRIDE + t] = v;
}

__global__ __launch_bounds__(256) void dmh_kernel(
    const float* __restrict__ E,          // (8, 8, 256, 256)
    const unsigned int* __restrict__ wpk, // packed weights, 96 dwords/match
    const float* __restrict__ centers,    // (256, 2)
    const int*   __restrict__ bidx,       // (256,)
    float* __restrict__ out)              // (256, 256, 256)
{
    const int m    = blockIdx.x >> 6;
    const int tile = blockIdx.x & 63;
    const int p0   = tile * 1024 + threadIdx.x * 4;

    const unsigned int* __restrict__ wm = wpk + m * WSTRIDE;  // wave-uniform -> s_load
    const float cx = centers[2 * m];
    const float cy = centers[2 * m + 1];
    const int   b  = bidx[m];
    const float* __restrict__ Eb = E + (size_t)b * (8 * HWPIX) + p0;

    const int h = p0 >> 8;
    const int w = p0 & 255;

    // ---- load E (coalesced float4) and pack input pairs along the channel dim ----
    // xp[p][j]: pair p of pixel j; p 0..3 = E channel pairs, p=4 = (rel_x, rel_y)
    half2_t xp[5][4];
    #pragma unroll
    for (int c = 0; c < 4; ++c) {
        const float4 a0 = *(const float4*)(Eb + (size_t)(2 * c)     * HWPIX);
        const float4 a1 = *(const float4*)(Eb + (size_t)(2 * c + 1) * HWPIX);
        xp[c][0] = __builtin_amdgcn_cvt_pkrtz(a0.x, a1.x);
        xp[c][1] = __builtin_amdgcn_cvt_pkrtz(a0.y, a1.y);
        xp[c][2] = __builtin_amdgcn_cvt_pkrtz(a0.z, a1.z);
        xp[c][3] = __builtin_amdgcn_cvt_pkrtz(a0.w, a1.w);
    }
    const float ry = (h + 0.5f) * (1.0f / 256.0f) - cy;
    #pragma unroll
    for (int j = 0; j < 4; ++j) {
        const float rx = (w + j + 0.5f) * (1.0f / 256.0f) - cx;
        xp[4][j] = __builtin_amdgcn_cvt_pkrtz(rx, ry);
    }

    // ---- Layer 0: 10 -> 8 via v_dot2_f32_f16 (fp32 accumulate) ----
    half2_t yp[4][4];
    #pragma unroll
    for (int oq = 0; oq < 4; ++oq) {
        float g[2][4];
        #pragma unroll
        for (int s = 0; s < 2; ++s) {
            const int o = 2 * oq + s;
            const float bias = __uint_as_float(wm[40 + o]);
            float a[4] = {bias, bias, bias, bias};
            #pragma unroll
            for (int p = 0; p < 5; ++p) {
                const half2_t wv = h2(wm[o * 5 + p]);
                #pragma unroll
                for (int j = 0; j < 4; ++j)
                    a[j] = __builtin_amdgcn_fdot2(wv, xp[p][j], a[j], false);
            }
            #pragma unroll
            for (int j = 0; j < 4; ++j) g[s][j] = gelu_fast(a[j]);
        }
        #pragma unroll
        for (int j = 0; j < 4; ++j)
            yp[oq][j] = __builtin_amdgcn_cvt_pkrtz(g[0][j], g[1][j]);
    }

    // ---- Layer 1: 8 -> 8 ----
    half2_t zp[4][4];
    #pragma unroll
    for (int oq = 0; oq < 4; ++oq) {
        float g[2][4];
        #pragma unroll
        for (int s = 0; s < 2; ++s) {
            const int o = 2 * oq + s;
            const float bias = __uint_as_float(wm[80 + o]);
            float a[4] = {bias, bias, bias, bias};
            #pragma unroll
            for (int p = 0; p < 4; ++p) {
                const half2_t wv = h2(wm[48 + o * 4 + p]);
                #pragma unroll
                for (int j = 0; j < 4; ++j)
                    a[j] = __builtin_amdgcn_fdot2(wv, yp[p][j], a[j], false);
            }
            #pragma unroll
            for (int j = 0; j < 4; ++j) g[s][j] = gelu_fast(a[j]);
        }
        #pragma unroll
        for (int j = 0; j < 4; ++j)
            zp[oq][j] = __builtin_amdgcn_cvt_pkrtz(g[0][j], g[1][j]);
    }

    // ---- Layer 2: 8 -> 1 ----
    const float b2 = __uint_as_float(wm[92]);
    float r[4] = {b2, b2, b2, b2};
    #pragma unroll
    for (int p = 0; p < 4; ++p) {
        const half2_t wv = h2(wm[88 + p]);
        #pragma unroll
        for (int j = 0; j < 4; ++j)
            r[j] = __builtin_amdgcn_fdot2(wv, zp[p][j], r[j], false);
    }

    float4 o4;
    o4.x = r[0]; o4.y = r[1]; o4.z = r[2]; o4.w = r[3];
    *(float4*)(out + (size_t)m * HWPIX + p0) = o4;
}

extern "C" void kernel_launch(void* const* d_in, const int* in_sizes, int n_in,
                              void* d_out, int out_size, void* d_ws, size_t ws_size,
                              hipStream_t stream) {
    const float* E       = (const float*)d_in[0];
    const float* theta   = (const float*)d_in[1];
    const float* centers = (const float*)d_in[2];
    const int*   bidx    = (const int*)d_in[3];
    float* out = (float*)d_out;
    unsigned int* wpk = (unsigned int*)d_ws;  // 256*96*4 = 96 KiB of scratch

    hipLaunchKernelGGL(prep_kernel, dim3(NMATCH), dim3(128), 0, stream, theta, wpk);
    hipLaunchKernelGGL(dmh_kernel, dim3(NMATCH * 64), dim3(256), 0, stream,
                       E, wpk, centers, bidx, out);
}

// Round 6
// 172.461 us; speedup vs baseline: 1.0879x; 1.0879x over previous
//
#include <hip/hip_runtime.h>
#include <math.h>

// Problem constants: B=8, D=8 (channels), H=256, W=256, M=256
#define HWPIX 65536
#define NMATCH 256
#define THETA_LEN 169

// Transcendental-free GELU:
//   gelu(x) = 0.5x + 0.5|x|·erf(|x|/sqrt2),  erf(z) ~= z·Q(z^2)
// Q fitted (Newton interp at Chebyshev nodes on s=z^2 in [0,7.03], i.e. |x|<=3.75)
// and rebased to u=|x|^2 with the 0.5/sqrt2 factor folded in:
//   gelu = 0.5x + |x|·a·(q0 + q1 u + q2 u^2 + q3 u^3 + q4 u^4),  a=min(|x|,3.75), u=a^2
// q0 nudged -4e-4 so the |x|>3.75 tail slope error ~cancels (err<=0.01 to |x|=16).
// Hand-verified: x=1 -> 0.84189 (true 0.84134), x=2 -> 1.94958 (1.95450),
// x=-1 -> -0.15811 (-0.15866), x=4 -> 4.0036 (3.99987). 10 full-rate VALU ops,
// zero quarter-rate transcendentals (vs 5 full + exp2 + rcp before).
__device__ __forceinline__ float gelu_fast(float x) {
    const float ax = fabsf(x);
    const float a  = fminf(ax, 3.75f);
    const float u  = a * a;
    float h = fmaf(u, 1.02997e-5f, -4.28057e-4f);
    h = fmaf(u, h, 7.05740e-3f);
    h = fmaf(u, h, -6.20045e-2f);
    h = fmaf(u, h, 3.973531e-1f);
    const float m = a * h;
    const float t = ax * m;
    return fmaf(x, 0.5f, t);
}

__global__ __launch_bounds__(256) void dmh_kernel(
    const float* __restrict__ E,       // (8, 8, 256, 256)
    const float* __restrict__ theta,   // (256, 169)
    const float* __restrict__ centers, // (256, 2)
    const int*   __restrict__ bidx,    // (256,)
    float* __restrict__ out)           // (256, 256, 256)
{
    // 64 blocks per match; each thread owns 4 consecutive pixels (same row).
    const int m    = blockIdx.x >> 6;
    const int tile = blockIdx.x & 63;
    const int p0   = tile * 1024 + threadIdx.x * 4;

    // All wave-uniform -> compiler emits s_load (SMEM/SGPR), no LDS needed.
    const float* __restrict__ th = theta + m * THETA_LEN;
    const float cx = centers[2 * m];
    const float cy = centers[2 * m + 1];
    const int   b  = bidx[m];
    const float* __restrict__ Eb = E + (size_t)b * (8 * HWPIX) + p0;

    const int h = p0 >> 8;
    const int w = p0 & 255;   // multiple of 4 -> 4 pixels share h

    // Inputs: 8 E channels (float4 per channel) + 2 rel channels.
    float x[10][4];
    #pragma unroll
    for (int c = 0; c < 8; ++c) {
        const float4 v = *(const float4*)(Eb + (size_t)c * HWPIX);
        x[c][0] = v.x; x[c][1] = v.y; x[c][2] = v.z; x[c][3] = v.w;
    }
    const float ry = (h + 0.5f) * (1.0f / 256.0f) - cy;
    #pragma unroll
    for (int j = 0; j < 4; ++j) {
        x[8][j] = (w + j + 0.5f) * (1.0f / 256.0f) - cx;  // rel_x varies with w
        x[9][j] = ry;                                     // rel_y constant in row
    }

    // Layer 0: 10 -> 8, w0 = th[0:80] (8,10), b0 = th[80:88]
    // Bias folded into the first FMA (1 v_mov per out instead of 4).
    float y[8][4];
    #pragma unroll
    for (int o = 0; o < 8; ++o) {
        const float bias = th[80 + o];
        const float w0   = th[o * 10];
        float a[4];
        #pragma unroll
        for (int j = 0; j < 4; ++j) a[j] = fmaf(w0, x[0][j], bias);
        #pragma unroll
        for (int i = 1; i < 10; ++i) {
            const float wv = th[o * 10 + i];   // SGPR operand, 4 uses per read
            #pragma unroll
            for (int j = 0; j < 4; ++j) a[j] = fmaf(wv, x[i][j], a[j]);
        }
        #pragma unroll
        for (int j = 0; j < 4; ++j) y[o][j] = gelu_fast(a[j]);
    }

    // Layer 1: 8 -> 8, w1 = th[88:152] (8,8), b1 = th[152:160]
    float z[8][4];
    #pragma unroll
    for (int o = 0; o < 8; ++o) {
        const float bias = th[152 + o];
        const float w0   = th[88 + o * 8];
        float a[4];
        #pragma unroll
        for (int j = 0; j < 4; ++j) a[j] = fmaf(w0, y[0][j], bias);
        #pragma unroll
        for (int i = 1; i < 8; ++i) {
            const float wv = th[88 + o * 8 + i];
            #pragma unroll
            for (int j = 0; j < 4; ++j) a[j] = fmaf(wv, y[i][j], a[j]);
        }
        #pragma unroll
        for (int j = 0; j < 4; ++j) z[o][j] = gelu_fast(a[j]);
    }

    // Layer 2: 8 -> 1, w2 = th[160:168], b2 = th[168]
    const float b2 = th[168];
    const float w20 = th[160];
    float r[4];
    #pragma unroll
    for (int j = 0; j < 4; ++j) r[j] = fmaf(w20, z[0][j], b2);
    #pragma unroll
    for (int i = 1; i < 8; ++i) {
        const float wv = th[160 + i];
        #pragma unroll
        for (int j = 0; j < 4; ++j) r[j] = fmaf(wv, z[i][j], r[j]);
    }

    float4 o4;
    o4.x = r[0]; o4.y = r[1]; o4.z = r[2]; o4.w = r[3];
    *(float4*)(out + (size_t)m * HWPIX + p0) = o4;
}

extern "C" void kernel_launch(void* const* d_in, const int* in_sizes, int n_in,
                              void* d_out, int out_size, void* d_ws, size_t ws_size,
                              hipStream_t stream) {
    const float* E       = (const float*)d_in[0];
    const float* theta   = (const float*)d_in[1];
    const float* centers = (const float*)d_in[2];
    const int*   bidx    = (const int*)d_in[3];
    float* out = (float*)d_out;

    dim3 grid(NMATCH * 64);  // 16384 blocks, 1024 px/block
    dim3 block(256);
    hipLaunchKernelGGL(dmh_kernel, grid, block, 0, stream, E, theta, centers, bidx, out);
}